// Round 9
// baseline (480.072 us; speedup 1.0000x reference)
//
#include <hip/hip_runtime.h>
#include <math.h>

// ---------------------------------------------------------------------------
// GATv2 x3 + LN + graph max-pool + MLP.
// Round 18: k_binB attr-mean rework. R15 added 3x atomicAdd(float) to LDS
// per edge (2.4M atomics, ~16-way same-address serialization at avg degree
// 16) -- prime suspect for the ~150us gap between tier-2 BW estimates
// (~125us) and measured non-agg time (~276us). Replaced with a cooperative
// pass AFTER placement: each node's real edges are contiguous in e4 and
// L2-hot; a 16-lane group strides the span (coalesced 256B/iter) and
// DPP-tree-reduces x/y/z. Placement keeps only the int atomicAdd.
// k_agg frozen (R15 loop, 63.8us); everything else R17-verbatim.
// ---------------------------------------------------------------------------

#define LN_EPS 1e-5f
#define LOG2E 1.44269504088896340736f
#define CHUNK 2048
#define BCAP 8192  // records per staging bucket (avg 4096)

typedef short bf16x8 __attribute__((ext_vector_type(8)));
typedef float f32x4 __attribute__((ext_vector_type(4)));
typedef float f32x2 __attribute__((ext_vector_type(2)));

static __device__ __forceinline__ unsigned short f2bf(float f) {
  unsigned int u = __float_as_uint(f);
  u += 0x7fffu + ((u >> 16) & 1u);  // RNE
  return (unsigned short)(u >> 16);
}

template <int CTRL>
static __device__ __forceinline__ float dpp_add(float v) {
  int x = __builtin_amdgcn_update_dpp(0, __float_as_int(v), CTRL, 0xf, 0xf, true);
  return v + __int_as_float(x);
}

// sum+broadcast over each 8-lane group: quad xor1, quad xor2, row_half_mirror
static __device__ __forceinline__ float dpp_sum8(float v) {
  v = dpp_add<0x0B1>(v);  // quad_perm 1,0,3,2
  v = dpp_add<0x04E>(v);  // quad_perm 2,3,0,1
  v = dpp_add<0x141>(v);  // row_half_mirror
  return v;
}

// sum+broadcast over each 16-lane row (quad xor1/xor2, half_mirror, mirror)
static __device__ __forceinline__ float dpp_sum16(float v) {
  v = dpp_add<0x0B1>(v);
  v = dpp_add<0x04E>(v);
  v = dpp_add<0x141>(v);  // row_half_mirror
  v = dpp_add<0x140>(v);  // row_mirror
  return v;
}

// ---------------- packed prologue: {binA | convW(packed) | pack} ----------------
// W fragment layout per matrix (16384 ushorts):
//   chunk c in [0,2048): lane=c&63, kt=(c>>6)&3, jt=c>>8
//   Wp[c*8+j] = W[(jt*16 + (lane&15))*128 + kt*32 + (lane>>4)*8 + j]
__global__ __launch_bounds__(256) void k_pre(
    const int* __restrict__ ei, const float* __restrict__ ea,
    int* __restrict__ gcnt, float4* __restrict__ staged, int E, int nbuk, int nbinA,
    const float* __restrict__ w0, const float* __restrict__ w1,
    const float* __restrict__ w2, const float* __restrict__ w3,
    const float* __restrict__ w4, const float* __restrict__ w5,
    unsigned short* __restrict__ Wb,
    const float* __restrict__ We0, const float* __restrict__ att0,
    const float* __restrict__ We1, const float* __restrict__ att1,
    const float* __restrict__ We2, const float* __restrict__ att2,
    float* __restrict__ tab) {
  __shared__ int hist[256];
  __shared__ int basebuf[256];
  int b = blockIdx.x;
  int t = threadIdx.x;

  if (b < nbinA) {
    // ---- binA: histogram edges into 256-node buckets, stage records ----
    int e0 = b * CHUNK;
    hist[t] = 0;
    __syncthreads();
#pragma unroll
    for (int i = 0; i < CHUNK / 256; ++i) {
      int e = e0 + i * 256 + t;
      if (e < E) atomicAdd(&hist[ei[E + e] >> 8], 1);
    }
    __syncthreads();
    int h = hist[t];
    if (t < nbuk && h > 0) basebuf[t] = t * BCAP + atomicAdd(&gcnt[t], h);
    hist[t] = 0;
    __syncthreads();
#pragma unroll
    for (int i = 0; i < CHUNK / 256; ++i) {
      int e = e0 + i * 256 + t;
      if (e < E) {
        int s = ei[e];
        int d = ei[E + e];
        int bk = d >> 8;
        int r = atomicAdd(&hist[bk], 1);
        float4 rec;
        rec.x = ea[e * 3 + 0];
        rec.y = ea[e * 3 + 1];
        rec.z = ea[e * 3 + 2];
        rec.w = __int_as_float(s | (d << 16));
        staged[basebuf[bk] + r] = rec;
      }
    }
  } else if (b < nbinA + 48) {
    // ---- convW packed: 6 matrices x 8 blocks; thread does one 8-elem chunk ----
    int bb = b - nbinA;
    const float* srcs[6] = {w0, w1, w2, w3, w4, w5};
    int mtx = bb >> 3;
    int c = (bb & 7) * 256 + t;  // chunk in [0,2048)
    int lane = c & 63;
    int kt = (c >> 6) & 3;
    int jt = c >> 8;
    const float* s = srcs[mtx] + (size_t)(jt * 16 + (lane & 15)) * 128 + kt * 32 + (lane >> 4) * 8;
    unsigned short* d = Wb + (size_t)mtx * 16384 + (size_t)c * 8;
#pragma unroll
    for (int j = 0; j < 8; ++j) d[j] = f2bf(s[j]);
  } else {
    // ---- pack: per-layer, per-lane score params ----
    if (t < 96) {
      int l = t >> 5;
      int sl = t & 31;
      const float* We = (l == 0) ? We0 : ((l == 1) ? We1 : We2);
      const float* att = (l == 0) ? att0 : ((l == 1) ? att1 : att2);
      float* o = tab + (size_t)l * 512 + sl * 16;
#pragma unroll
      for (int j = 0; j < 4; ++j) {
        o[j] = We[(sl * 4 + j) * 3 + 0];
        o[4 + j] = We[(sl * 4 + j) * 3 + 1];
        o[8 + j] = We[(sl * 4 + j) * 3 + 2];
        o[12 + j] = att[sl * 4 + j] * LOG2E;
      }
    }
  }
}

// ---------------- binB + folded bucket-prefix scan; cooperative attr means ----------------
__global__ __launch_bounds__(256) void k_binB(const float4* __restrict__ staged,
                                              const int* __restrict__ gcnt,
                                              float4* __restrict__ e4,
                                              int* __restrict__ offs, int N, int nbuk, int EP) {
  __shared__ int hist[256], cur[256], begS[256], sh[256];
  int t = threadIdx.x;
  int b = blockIdx.x;
  int n0 = b * 256;
  int nn = min(256, N - n0);
  int m = gcnt[b];
  size_t sbase = (size_t)b * BCAP;

  // ---- global bucket prefix (each block computes locally; removes k_bscan) ----
  {
    int nodes_t = (t < nbuk) ? min(256, N - t * 256) : 0;
    int v0 = (t < nbuk) ? gcnt[t] + nodes_t : 0;
    sh[t] = v0;
    __syncthreads();
    for (int d = 1; d < 256; d <<= 1) {
      int add = (t >= d) ? sh[t - d] : 0;
      __syncthreads();
      sh[t] += add;
      __syncthreads();
    }
  }
  int bukStart_b = (b == 0) ? 0 : sh[b - 1];
  if (b == 0) {
    if (t == 0) offs[N] = EP;
    if (t < 8) {  // pad records: valid gather offset (row 0), finite attrs
      float4 r;
      r.x = 0.f; r.y = 0.f; r.z = 0.f;
      r.w = __int_as_float(0);
      e4[EP + t] = r;
    }
  }
  __syncthreads();

  // ---- per-node histogram within bucket ----
  hist[t] = 0;
  __syncthreads();
  for (int p = t; p < m; p += 256) {
    unsigned int u = (unsigned int)__float_as_int(staged[sbase + p].w);
    atomicAdd(&hist[(int)(u >> 16) - n0], 1);
  }
  __syncthreads();
  int v = (t < nn) ? hist[t] + 1 : 0;
  sh[t] = v;
  __syncthreads();
  for (int d = 1; d < 256; d <<= 1) {
    int add = (t >= d) ? sh[t - d] : 0;
    __syncthreads();
    sh[t] += add;
    __syncthreads();
  }
  if (t < nn) {
    int base = bukStart_b + sh[t] - v;
    cur[t] = base;
    begS[t] = base;
    offs[n0 + t] = base;
  }
  __syncthreads();
  // ---- placement (int atomic only; attr sums moved to cooperative pass) ----
  for (int p = t; p < m; p += 256) {
    float4 rec = staged[sbase + p];
    unsigned int u = (unsigned int)__float_as_int(rec.w);
    int d = (int)(u >> 16) - n0;
    int pos = atomicAdd(&cur[d], 1);
    rec.w = __int_as_float((int)(u & 0xffffu) * 256);
    e4[pos] = rec;
  }
  __syncthreads();
  // ---- self-loop means: 16-lane group per node, coalesced span reads (L2-hot) ----
  {
    int wave = t >> 6;
    int lane = t & 63;
    int g = lane >> 4;
    int sub = lane & 15;
#pragma unroll
    for (int i = 0; i < 16; ++i) {
      int nd = wave * 64 + i * 4 + g;
      if (nd < nn) {
        int beg = begS[nd], last = cur[nd];  // [beg,last) = real edges; last = self-loop slot
        float sx = 0.f, sy = 0.f, sz = 0.f;
        for (int p = beg + sub; p < last; p += 16) {
          float4 r = e4[p];
          sx += r.x; sy += r.y; sz += r.z;
        }
        sx = dpp_sum16(sx);
        sy = dpp_sum16(sy);
        sz = dpp_sum16(sz);
        if (sub == 0) {
          float invc = 1.0f / fmaxf((float)(last - beg), 1.0f);
          float4 r;
          r.x = sx * invc;
          r.y = sy * invc;
          r.z = sz * invc;
          r.w = __int_as_float((n0 + nd) * 256);
          e4[last] = r;
        }
      }
    }
  }
}

// ---------------- merged MFMA GEMM: xl AND xr in one pass ----------------
// A = W in fragment-packed layout (coalesced lane*16B loads). B = x:
//   layer 0 reads f32 x_in rows (+in-register RNE convert);
//   layers 1,2 read xpack (fragment-packed by k_agg's epilogue) coalesced.
// Stores via per-wave LDS transpose -> 4x dwordx4 coalesced per matrix.
template <bool F32IN>
__global__ __launch_bounds__(256) void k_gemm_fused(const float* __restrict__ xf,
                                                    const unsigned short* __restrict__ xpack,
                                                    const unsigned short* __restrict__ Wb,
                                                    const float* __restrict__ bl,
                                                    const float* __restrict__ br,
                                                    unsigned short* __restrict__ xlb,
                                                    unsigned short* __restrict__ xrb, int N) {
  __shared__ unsigned short sld[4][2048];  // per-wave 16 nodes x 128ch
  int wave = threadIdx.x >> 6;
  int lane = threadIdx.x & 63;
  const unsigned short* WL = Wb;
  const unsigned short* WR = Wb + 16384;

  int row0 = (blockIdx.x * 4 + wave) * 16;
  if (row0 >= N) return;
  int m = lane & 15;
  int q = lane >> 4;

  bf16x8 bfrag[4];
  if constexpr (F32IN) {
    int brow = row0 + m;
    if (brow >= N) brow = N - 1;
    const float* xrow = xf + (size_t)brow * 128 + q * 8;
#pragma unroll
    for (int kt = 0; kt < 4; ++kt) {
      float4 u0 = *(const float4*)(xrow + kt * 32);
      float4 u1 = *(const float4*)(xrow + kt * 32 + 4);
      bf16x8 f;
      f[0] = (short)f2bf(u0.x); f[1] = (short)f2bf(u0.y);
      f[2] = (short)f2bf(u0.z); f[3] = (short)f2bf(u0.w);
      f[4] = (short)f2bf(u1.x); f[5] = (short)f2bf(u1.y);
      f[6] = (short)f2bf(u1.z); f[7] = (short)f2bf(u1.w);
      bfrag[kt] = f;
    }
  } else {
    const unsigned short* xrow = xpack + (size_t)(row0 >> 4) * 2048 + lane * 8;
#pragma unroll
    for (int kt = 0; kt < 4; ++kt) bfrag[kt] = *(const bf16x8*)(xrow + kt * 512);
  }

  f32x4 accL[8], accR[8];
#pragma unroll
  for (int jt = 0; jt < 8; ++jt) {
    accL[jt] = (f32x4){0.f, 0.f, 0.f, 0.f};
    accR[jt] = (f32x4){0.f, 0.f, 0.f, 0.f};
  }

#pragma unroll
  for (int kt = 0; kt < 4; ++kt) {
#pragma unroll
    for (int jt = 0; jt < 8; ++jt) {
      bf16x8 aL = *(const bf16x8*)(WL + (size_t)(jt * 4 + kt) * 512 + lane * 8);
      accL[jt] = __builtin_amdgcn_mfma_f32_16x16x32_bf16(aL, bfrag[kt], accL[jt], 0, 0, 0);
      bf16x8 aR = *(const bf16x8*)(WR + (size_t)(jt * 4 + kt) * 512 + lane * 8);
      accR[jt] = __builtin_amdgcn_mfma_f32_16x16x32_bf16(aR, bfrag[kt], accR[jt], 0, 0, 0);
    }
  }

  // ---- L: pack+bias -> LDS transpose -> coalesced stores ----
#pragma unroll
  for (int jt = 0; jt < 8; ++jt) {
    float4 bs = *(const float4*)&bl[jt * 16 + q * 4];
    uint2 p;
    p.x = (unsigned int)f2bf(accL[jt][0] + bs.x) | ((unsigned int)f2bf(accL[jt][1] + bs.y) << 16);
    p.y = (unsigned int)f2bf(accL[jt][2] + bs.z) | ((unsigned int)f2bf(accL[jt][3] + bs.w) << 16);
    *(uint2*)&sld[wave][m * 128 + jt * 16 + q * 4] = p;
  }
#pragma unroll
  for (int r = 0; r < 4; ++r) {
    uint4 vv = *(const uint4*)&sld[wave][r * 512 + lane * 8];
    int node = row0 + r * 4 + (lane >> 4);
    if (node < N) *(uint4*)(xlb + (size_t)row0 * 128 + r * 512 + lane * 8) = vv;
  }
  // ---- R: reuse LDS ----
#pragma unroll
  for (int jt = 0; jt < 8; ++jt) {
    float4 bs = *(const float4*)&br[jt * 16 + q * 4];
    uint2 p;
    p.x = (unsigned int)f2bf(accR[jt][0] + bs.x) | ((unsigned int)f2bf(accR[jt][1] + bs.y) << 16);
    p.y = (unsigned int)f2bf(accR[jt][2] + bs.z) | ((unsigned int)f2bf(accR[jt][3] + bs.w) << 16);
    *(uint2*)&sld[wave][m * 128 + jt * 16 + q * 4] = p;
  }
#pragma unroll
  for (int r = 0; r < 4; ++r) {
    uint4 vv = *(const uint4*)&sld[wave][r * 512 + lane * 8];
    int node = row0 + r * 4 + (lane >> 4);
    if (node < N) *(uint4*)(xrb + (size_t)row0 * 128 + r * 512 + lane * 8) = vv;
  }
}

// ---------------- fused: score + softmax(exp2) + weighted agg + epilogue ----------------
// one wave per node; lanes 0-31 = edge p, lanes 32-63 = edge p+1 (same node);
// each lane owns 4 channels c = (lane&31)*4; head group = 8 lanes.
// (R15 version verbatim -- proven best; loop frozen.)
__global__ __launch_bounds__(256) void k_agg(const unsigned short* __restrict__ xlb,
                                             const unsigned short* __restrict__ xrb,
                                             const float4* __restrict__ e4,
                                             const int* __restrict__ offs,
                                             const float* __restrict__ scoreTab,
                                             const float* __restrict__ bo,
                                             const float* __restrict__ lng, const float* __restrict__ lnb,
                                             unsigned short* __restrict__ xnext_pack,
                                             float* __restrict__ emb, int last, int N) {
  int w = (blockIdx.x * blockDim.x + threadIdx.x) >> 6;
  if (w >= N) return;
  int lane = threadIdx.x & 63;
  int half = lane >> 5;
  int sl = lane & 31;
  int c = sl * 4;
  unsigned int c2 = (unsigned int)(c * 2);  // byte offset into bf16 row
  int beg = offs[w], end = offs[w + 1];
  int cnt = end - beg;

  // packed per-lane params as float2 halves (channels 01 / 23)
  f32x2 xr01, xr23, wea01, wea23, web01, web23, wec01, wec23, at01, at23;
  {
    const float4* tp = (const float4*)(scoreTab + (size_t)sl * 16);
    float4 pa = tp[0], pb = tp[1], pc = tp[2], pt = tp[3];
    wea01[0] = pa.x; wea01[1] = pa.y; wea23[0] = pa.z; wea23[1] = pa.w;
    web01[0] = pb.x; web01[1] = pb.y; web23[0] = pb.z; web23[1] = pb.w;
    wec01[0] = pc.x; wec01[1] = pc.y; wec23[0] = pc.z; wec23[1] = pc.w;
    at01[0] = pt.x; at01[1] = pt.y; at23[0] = pt.z; at23[1] = pt.w;
    uint2 vr = *(const uint2*)&xrb[(size_t)w * 128 + c];
    xr01[0] = __uint_as_float(vr.x << 16);
    xr01[1] = __uint_as_float(vr.x & 0xffff0000u);
    xr23[0] = __uint_as_float(vr.y << 16);
    xr23[1] = __uint_as_float(vr.y & 0xffff0000u);
  }

  const char* e4B = (const char*)e4;
  const char* xlB = (const char*)xlb;

  float l = 0.f;
  f32x2 acc01 = {0.f, 0.f}, acc23 = {0.f, 0.f};

  unsigned int lastoff = (unsigned int)(end - 1) << 4;
  int T = (cnt + 1) >> 1;  // pair iterations

  // ---- pipeline prologue: records for pairs 0..2, gathers for pairs 0..1 ----
  unsigned int o0 = (unsigned int)(beg + half) << 4;
  if (o0 > lastoff) o0 = lastoff;  // cnt==1, half 1 clamps
  unsigned int o1 = o0 + 32u;
  if (o1 > lastoff) o1 = lastoff;
  unsigned int o2 = o1 + 32u;
  if (o2 > lastoff) o2 = lastoff;
  float4 e0 = *(const float4*)(e4B + o0);
  float4 e1 = *(const float4*)(e4B + o1);
  float4 e2 = *(const float4*)(e4B + o2);
  uint2 g0 = *(const uint2*)(xlB + ((unsigned int)__float_as_int(e0.w) + c2));
  uint2 g1 = *(const uint2*)(xlB + ((unsigned int)__float_as_int(e1.w) + c2));
  unsigned int offP = o2;

  // one edge: unpack gather, score (packed f32), exp2, accumulate.
  auto compute = [&](const float4& e, uint2 v, bool valid) {
    f32x2 xl01, xl23;
    xl01[0] = __uint_as_float(v.x << 16);
    xl01[1] = __uint_as_float(v.x & 0xffff0000u);
    xl23[0] = __uint_as_float(v.y << 16);
    xl23[1] = __uint_as_float(v.y & 0xffff0000u);
    f32x2 ex = {e.x, e.x}, ey = {e.y, e.y}, ez = {e.z, e.z};
    f32x2 t01 = __builtin_elementwise_fma(wea01, ex,
                  __builtin_elementwise_fma(web01, ey,
                    __builtin_elementwise_fma(wec01, ez, xr01 + xl01)));
    f32x2 t23 = __builtin_elementwise_fma(wea23, ex,
                  __builtin_elementwise_fma(web23, ey,
                    __builtin_elementwise_fma(wec23, ez, xr23 + xl23)));
    t01 = __builtin_elementwise_max(t01, t01 * 0.2f);
    t23 = __builtin_elementwise_max(t23, t23 * 0.2f);
    f32x2 d2 = __builtin_elementwise_fma(t01, at01, t23 * at23);
    float s = d2[0] + d2[1];
    float wgt = __builtin_amdgcn_exp2f(dpp_sum8(s));
    if (!valid) wgt = 0.f;
    l += wgt;
    f32x2 w2 = {wgt, wgt};
    acc01 = __builtin_elementwise_fma(xl01, w2, acc01);
    acc23 = __builtin_elementwise_fma(xl23, w2, acc23);
  };

  // ---- steady state: record(i+3), gather(i+2), compute(i) ----
#pragma unroll 2
  for (int it = 0; it < T - 3; ++it) {
    unsigned int o3 = offP + 32u;
    if (o3 > lastoff) o3 = lastoff;
    float4 e3 = *(const float4*)(e4B + o3);
    uint2 g2 = *(const uint2*)(xlB + ((unsigned int)__float_as_int(e2.w) + c2));
    compute(e0, g0, true);
    e0 = e1; e1 = e2; e2 = e3;
    g0 = g1; g1 = g2;
    offP = o3;
  }
  if (T >= 3) {  // pair T-3: issue last gather, compute
    uint2 g2 = *(const uint2*)(xlB + ((unsigned int)__float_as_int(e2.w) + c2));
    compute(e0, g0, true);
    e0 = e1; e1 = e2;
    g0 = g1; g1 = g2;
  }
  if (T >= 2) {  // pair T-2 (always fully valid)
    compute(e0, g0, true);
    e0 = e1;
    g0 = g1;
  }
  {  // pair T-1 (masked: odd cnt leaves half==1 invalid)
    int idx = 2 * (T - 1) + half;
    compute(e0, g0, idx < cnt);
  }

  // combine halves
  l += __shfl_xor(l, 32);
  float a0 = acc01[0]; a0 += __shfl_xor(a0, 32);
  float a1 = acc01[1]; a1 += __shfl_xor(a1, 32);
  float a2 = acc23[0]; a2 += __shfl_xor(a2, 32);
  float a3 = acc23[1]; a3 += __shfl_xor(a3, 32);

  float inv = 1.0f / l;
  f32x4 o4;
  const float4 bo4 = *(const float4*)&bo[c];
  o4[0] = a0 * inv + bo4.x;
  o4[1] = a1 * inv + bo4.y;
  o4[2] = a2 * inv + bo4.z;
  o4[3] = a3 * inv + bo4.w;

  if (last) {
    if (half == 0) {
      float4 st = {o4[0], o4[1], o4[2], o4[3]};
      *(float4*)&emb[(size_t)w * 128 + c] = st;
    }
  } else {
    f32x4 r;
    r[0] = fmaxf(o4[0], 0.f);
    r[1] = fmaxf(o4[1], 0.f);
    r[2] = fmaxf(o4[2], 0.f);
    r[3] = fmaxf(o4[3], 0.f);
    float s = r[0] + r[1] + r[2] + r[3];
    s += __shfl_xor(s, 1);
    s += __shfl_xor(s, 2);
    s += __shfl_xor(s, 4);
    s += __shfl_xor(s, 8);
    s += __shfl_xor(s, 16);
    float mu = s * 0.0078125f;  // /128
    f32x4 d;
    d[0] = r[0] - mu;
    d[1] = r[1] - mu;
    d[2] = r[2] - mu;
    d[3] = r[3] - mu;
    float v2 = d[0] * d[0] + d[1] * d[1] + d[2] * d[2] + d[3] * d[3];
    v2 += __shfl_xor(v2, 1);
    v2 += __shfl_xor(v2, 2);
    v2 += __shfl_xor(v2, 4);
    v2 += __shfl_xor(v2, 8);
    v2 += __shfl_xor(v2, 16);
    float var = v2 * 0.0078125f;
    float rstd = rsqrtf(var + LN_EPS);
    if (half == 0) {
      const float4 g4 = *(const float4*)&lng[c];
      const float4 b4 = *(const float4*)&lnb[c];
      float o0 = d[0] * rstd * g4.x + b4.x;
      float o1 = d[1] * rstd * g4.y + b4.y;
      float o2 = d[2] * rstd * g4.z + b4.z;
      float o3 = d[3] * rstd * g4.w + b4.w;
      uint2 pack;
      pack.x = (unsigned int)f2bf(o0) | ((unsigned int)f2bf(o1) << 16);
      pack.y = (unsigned int)f2bf(o2) | ((unsigned int)f2bf(o3) << 16);
      // fragment-packed write: node w -> block B=w>>4, m=w&15;
      // channels c..c+3: kt=sl>>3, q=(sl>>1)&3, half8=(sl&1)*4
      int kt = sl >> 3;
      int qq = (sl >> 1) & 3;
      size_t elem = (size_t)(w >> 4) * 2048 + kt * 512 + (qq * 16 + (w & 15)) * 8 + (sl & 1) * 4;
      *(uint2*)&xnext_pack[elem] = pack;
    }
  }
}

// ---------------- graph max-pool (relu implicit: atomicMax vs 0-init) ----------------
__global__ void k_pool(const float* __restrict__ emb, const int* __restrict__ batch,
                       float* __restrict__ pooled, int N) {
  int c = threadIdx.x & 127;
  int half = threadIdx.x >> 7;
  int base = blockIdx.x * 64 + half;
  int limit = min(blockIdx.x * 64 + 64, N);
  float cur = 0.f;
  int curg = -1;
  for (int n = base; n < limit; n += 2) {
    int g = batch[n];
    if (g != curg) {
      if (curg >= 0) atomicMax((unsigned int*)&pooled[curg * 128 + c], __float_as_uint(cur));
      curg = g;
      cur = 0.f;
    }
    cur = fmaxf(cur, emb[(size_t)n * 128 + c]);
  }
  if (curg >= 0) atomicMax((unsigned int*)&pooled[curg * 128 + c], __float_as_uint(cur));
}

// ---------------- MLP: 128 -> 32 -> 32 -> 32 -> 1 ----------------
__global__ void k_mlp(const float* __restrict__ pooled,
                      const float* __restrict__ pw1, const float* __restrict__ pb1,
                      const float* __restrict__ pw2, const float* __restrict__ pb2,
                      const float* __restrict__ pw3, const float* __restrict__ pb3,
                      const float* __restrict__ pw4, const float* __restrict__ pb4,
                      float* __restrict__ out) {
  int g = blockIdx.x;
  int t = threadIdx.x;  // 64 threads
  __shared__ float buf1[32], buf2[32];
  if (t < 32) {
    float acc = pb1[t];
    for (int k = 0; k < 128; ++k) acc += pw1[t * 128 + k] * pooled[g * 128 + k];
    buf1[t] = fmaxf(acc, 0.f);
  }
  __syncthreads();
  if (t < 32) {
    float acc = pb2[t];
    for (int k = 0; k < 32; ++k) acc += pw2[t * 32 + k] * buf1[k];
    buf2[t] = fmaxf(acc, 0.f);
  }
  __syncthreads();
  if (t < 32) {
    float acc = pb3[t];
    for (int k = 0; k < 32; ++k) acc += pw3[t * 32 + k] * buf2[k];
    buf1[t] = fmaxf(acc, 0.f);
  }
  __syncthreads();
  if (t == 0) {
    float acc = pb4[0];
    for (int k = 0; k < 32; ++k) acc += pw4[k] * buf1[k];
    out[g] = acc;
  }
}

// ---------------------------------------------------------------------------

extern "C" void kernel_launch(void* const* d_in, const int* in_sizes, int n_in,
                              void* d_out, int out_size, void* d_ws, size_t ws_size,
                              hipStream_t stream) {
  const float* x_in = (const float*)d_in[0];
  const int* ei = (const int*)d_in[1];
  const int* batch = (const int*)d_in[2];
  const float* ea = (const float*)d_in[3];

  const int N = in_sizes[0] / 128;
  const int E = in_sizes[1] / 2;
  const int EP = E + N;
  const int G = out_size - N * 128;
  const int NBUK = (N + 255) / 256;
  const int NBINA = (E + CHUNK - 1) / CHUNK;

  const float *Wl[3], *bl[3], *Wr[3], *br[3], *We[3], *att[3], *bo[3];
  for (int l = 0; l < 3; ++l) {
    Wl[l] = (const float*)d_in[4 + 7 * l];
    bl[l] = (const float*)d_in[5 + 7 * l];
    Wr[l] = (const float*)d_in[6 + 7 * l];
    br[l] = (const float*)d_in[7 + 7 * l];
    We[l] = (const float*)d_in[8 + 7 * l];
    att[l] = (const float*)d_in[9 + 7 * l];
    bo[l] = (const float*)d_in[10 + 7 * l];
  }
  const float* lng[2] = {(const float*)d_in[25], (const float*)d_in[27]};
  const float* lnb[2] = {(const float*)d_in[26], (const float*)d_in[28]};
  const float* pw1 = (const float*)d_in[29];
  const float* pb1 = (const float*)d_in[30];
  const float* pw2 = (const float*)d_in[31];
  const float* pb2 = (const float*)d_in[32];
  const float* pw3 = (const float*)d_in[33];
  const float* pb3 = (const float*)d_in[34];
  const float* pw4 = (const float*)d_in[35];
  const float* pb4 = (const float*)d_in[36];

  char* base = (char*)d_ws;
  size_t cur = 0;
  auto carve = [&](size_t bytes) -> char* {
    char* p = base + cur;
    cur += (bytes + 255) & ~(size_t)255;
    return p;
  };
  unsigned short* xlb = (unsigned short*)carve((size_t)N * 128 * 2);
  unsigned short* xrb = (unsigned short*)carve((size_t)N * 128 * 2);
  // xpack: fragment-packed inter-layer activations; +1 block slack for tail
  unsigned short* xpack = (unsigned short*)carve(((size_t)((N + 15) / 16) + 1) * 2048 * 2);
  unsigned short* Wb = (unsigned short*)carve((size_t)6 * 16384 * 2);
  float4* e4 = (float4*)carve((size_t)(EP + 8) * 16);  // +8 pad records
  float4* staged = (float4*)carve((size_t)NBUK * BCAP * 16);
  int* offs = (int*)carve((size_t)(N + 1) * 4);
  int* gcnt = (int*)carve((size_t)NBUK * 4);
  float* scoreTab = (float*)carve((size_t)3 * 512 * 4);
  float* pooled = (float*)carve((size_t)G * 128 * 4);

  float* emb_out = (float*)d_out;
  float* mlp_out = (float*)d_out + (size_t)N * 128;

  hipMemsetAsync(gcnt, 0, (size_t)NBUK * 4, stream);
  hipMemsetAsync(pooled, 0, (size_t)G * 128 * 4, stream);

  // packed prologue: binA blocks + packed-convW blocks + 1 pack block
  k_pre<<<NBINA + 48 + 1, 256, 0, stream>>>(ei, ea, gcnt, staged, E, NBUK, NBINA,
                                            Wl[0], Wr[0], Wl[1], Wr[1], Wl[2], Wr[2], Wb,
                                            We[0], att[0], We[1], att[1], We[2], att[2],
                                            scoreTab);
  k_binB<<<NBUK, 256, 0, stream>>>(staged, gcnt, e4, offs, N, NBUK, EP);

  for (int l = 0; l < 3; ++l) {
    dim3 ggrid((N + 63) / 64);
    if (l == 0) {
      k_gemm_fused<true><<<ggrid, 256, 0, stream>>>(x_in, xpack, Wb, bl[0], br[0], xlb, xrb, N);
    } else {
      k_gemm_fused<false><<<ggrid, 256, 0, stream>>>(nullptr, xpack, Wb + (size_t)l * 32768,
                                                     bl[l], br[l], xlb, xrb, N);
    }
    int last = (l == 2) ? 1 : 0;
    const float* g = last ? bo[l] : lng[l];
    const float* b = last ? bo[l] : lnb[l];
    k_agg<<<(N * 64 + 255) / 256, 256, 0, stream>>>(xlb, xrb, e4, offs,
                                                    scoreTab + (size_t)l * 512,
                                                    bo[l], g, b,
                                                    xpack, emb_out, last, N);
  }

  k_pool<<<(N + 63) / 64, 256, 0, stream>>>(emb_out, batch, pooled, N);
  k_mlp<<<G, 64, 0, stream>>>(pooled, pw1, pb1, pw2, pb2, pw3, pb3, pw4, pb4, mlp_out);
}

// Round 10
// 472.299 us; speedup vs baseline: 1.0165x; 1.0165x over previous
//
#include <hip/hip_runtime.h>
#include <math.h>

// ---------------------------------------------------------------------------
// GATv2 x3 + LN + graph max-pool + MLP.
// Round 19: LOCK IN best-known config = R17 exact (468.2us session best).
// R18's cooperative attr-mean reverted: +12us (the R15 LDS atomics were
// hidden under placement-pass global traffic; the replacement's extra sync
// + global re-reads cost as much). binB atomic theory falsified.
// Session state: k_agg frozen at R15 loop (6 structural attempts all
// neutral-to-worse: latency/issue equilibrium at ~64us, 64% VALU / 22%
// HBM); tier-2 kernels all < top-5 visibility (<63us each); remaining
// unexplained ~190us consistent with fixed harness reset-dispatch overhead
// (launch-cut R14 and atomic-cut R18 both null).
// ---------------------------------------------------------------------------

#define LN_EPS 1e-5f
#define LOG2E 1.44269504088896340736f
#define CHUNK 2048
#define BCAP 8192  // records per staging bucket (avg 4096)

typedef short bf16x8 __attribute__((ext_vector_type(8)));
typedef float f32x4 __attribute__((ext_vector_type(4)));
typedef float f32x2 __attribute__((ext_vector_type(2)));

static __device__ __forceinline__ unsigned short f2bf(float f) {
  unsigned int u = __float_as_uint(f);
  u += 0x7fffu + ((u >> 16) & 1u);  // RNE
  return (unsigned short)(u >> 16);
}

// sum+broadcast over each 8-lane group: quad xor1, quad xor2, row_half_mirror
static __device__ __forceinline__ float dpp_sum8(float v) {
  int x;
  x = __builtin_amdgcn_update_dpp(0, __float_as_int(v), 0x0B1, 0xf, 0xf, true);  // quad_perm 1,0,3,2
  v += __int_as_float(x);
  x = __builtin_amdgcn_update_dpp(0, __float_as_int(v), 0x04E, 0xf, 0xf, true);  // quad_perm 2,3,0,1
  v += __int_as_float(x);
  x = __builtin_amdgcn_update_dpp(0, __float_as_int(v), 0x141, 0xf, 0xf, true);  // row_half_mirror
  v += __int_as_float(x);
  return v;
}

// ---------------- packed prologue: {binA | convW(packed) | pack} ----------------
// W fragment layout per matrix (16384 ushorts):
//   chunk c in [0,2048): lane=c&63, kt=(c>>6)&3, jt=c>>8
//   Wp[c*8+j] = W[(jt*16 + (lane&15))*128 + kt*32 + (lane>>4)*8 + j]
__global__ __launch_bounds__(256) void k_pre(
    const int* __restrict__ ei, const float* __restrict__ ea,
    int* __restrict__ gcnt, float4* __restrict__ staged, int E, int nbuk, int nbinA,
    const float* __restrict__ w0, const float* __restrict__ w1,
    const float* __restrict__ w2, const float* __restrict__ w3,
    const float* __restrict__ w4, const float* __restrict__ w5,
    unsigned short* __restrict__ Wb,
    const float* __restrict__ We0, const float* __restrict__ att0,
    const float* __restrict__ We1, const float* __restrict__ att1,
    const float* __restrict__ We2, const float* __restrict__ att2,
    float* __restrict__ tab) {
  __shared__ int hist[256];
  __shared__ int basebuf[256];
  int b = blockIdx.x;
  int t = threadIdx.x;

  if (b < nbinA) {
    // ---- binA: histogram edges into 256-node buckets, stage records ----
    int e0 = b * CHUNK;
    hist[t] = 0;
    __syncthreads();
#pragma unroll
    for (int i = 0; i < CHUNK / 256; ++i) {
      int e = e0 + i * 256 + t;
      if (e < E) atomicAdd(&hist[ei[E + e] >> 8], 1);
    }
    __syncthreads();
    int h = hist[t];
    if (t < nbuk && h > 0) basebuf[t] = t * BCAP + atomicAdd(&gcnt[t], h);
    hist[t] = 0;
    __syncthreads();
#pragma unroll
    for (int i = 0; i < CHUNK / 256; ++i) {
      int e = e0 + i * 256 + t;
      if (e < E) {
        int s = ei[e];
        int d = ei[E + e];
        int bk = d >> 8;
        int r = atomicAdd(&hist[bk], 1);
        float4 rec;
        rec.x = ea[e * 3 + 0];
        rec.y = ea[e * 3 + 1];
        rec.z = ea[e * 3 + 2];
        rec.w = __int_as_float(s | (d << 16));
        staged[basebuf[bk] + r] = rec;
      }
    }
  } else if (b < nbinA + 48) {
    // ---- convW packed: 6 matrices x 8 blocks; thread does one 8-elem chunk ----
    int bb = b - nbinA;
    const float* srcs[6] = {w0, w1, w2, w3, w4, w5};
    int mtx = bb >> 3;
    int c = (bb & 7) * 256 + t;  // chunk in [0,2048)
    int lane = c & 63;
    int kt = (c >> 6) & 3;
    int jt = c >> 8;
    const float* s = srcs[mtx] + (size_t)(jt * 16 + (lane & 15)) * 128 + kt * 32 + (lane >> 4) * 8;
    unsigned short* d = Wb + (size_t)mtx * 16384 + (size_t)c * 8;
#pragma unroll
    for (int j = 0; j < 8; ++j) d[j] = f2bf(s[j]);
  } else {
    // ---- pack: per-layer, per-lane score params ----
    if (t < 96) {
      int l = t >> 5;
      int sl = t & 31;
      const float* We = (l == 0) ? We0 : ((l == 1) ? We1 : We2);
      const float* att = (l == 0) ? att0 : ((l == 1) ? att1 : att2);
      float* o = tab + (size_t)l * 512 + sl * 16;
#pragma unroll
      for (int j = 0; j < 4; ++j) {
        o[j] = We[(sl * 4 + j) * 3 + 0];
        o[4 + j] = We[(sl * 4 + j) * 3 + 1];
        o[8 + j] = We[(sl * 4 + j) * 3 + 2];
        o[12 + j] = att[sl * 4 + j] * LOG2E;
      }
    }
  }
}

// ---------------- binB + folded bucket-prefix scan + LDS attr sums ----------------
__global__ __launch_bounds__(256) void k_binB(const float4* __restrict__ staged,
                                              const int* __restrict__ gcnt,
                                              float4* __restrict__ e4,
                                              int* __restrict__ offs, int N, int nbuk, int EP) {
  __shared__ int hist[256], cur[256], begS[256], sh[256];
  __shared__ float sX[256], sY[256], sZ[256];
  int t = threadIdx.x;
  int b = blockIdx.x;
  int n0 = b * 256;
  int nn = min(256, N - n0);
  int m = gcnt[b];
  size_t sbase = (size_t)b * BCAP;

  // ---- global bucket prefix (each block computes locally; removes k_bscan) ----
  {
    int nodes_t = (t < nbuk) ? min(256, N - t * 256) : 0;
    int v0 = (t < nbuk) ? gcnt[t] + nodes_t : 0;
    sh[t] = v0;
    __syncthreads();
    for (int d = 1; d < 256; d <<= 1) {
      int add = (t >= d) ? sh[t - d] : 0;
      __syncthreads();
      sh[t] += add;
      __syncthreads();
    }
  }
  int bukStart_b = (b == 0) ? 0 : sh[b - 1];
  if (b == 0) {
    if (t == 0) offs[N] = EP;
    if (t < 8) {  // pad records: valid gather offset (row 0), finite attrs
      float4 r;
      r.x = 0.f; r.y = 0.f; r.z = 0.f;
      r.w = __int_as_float(0);
      e4[EP + t] = r;
    }
  }
  __syncthreads();

  // ---- per-node histogram within bucket ----
  hist[t] = 0;
  sX[t] = 0.f; sY[t] = 0.f; sZ[t] = 0.f;
  __syncthreads();
  for (int p = t; p < m; p += 256) {
    unsigned int u = (unsigned int)__float_as_int(staged[sbase + p].w);
    atomicAdd(&hist[(int)(u >> 16) - n0], 1);
  }
  __syncthreads();
  int v = (t < nn) ? hist[t] + 1 : 0;
  sh[t] = v;
  __syncthreads();
  for (int d = 1; d < 256; d <<= 1) {
    int add = (t >= d) ? sh[t - d] : 0;
    __syncthreads();
    sh[t] += add;
    __syncthreads();
  }
  if (t < nn) {
    int base = bukStart_b + sh[t] - v;
    cur[t] = base;
    begS[t] = base;
    offs[n0 + t] = base;
  }
  __syncthreads();
  // ---- placement + attr sums (LDS atomics) ----
  for (int p = t; p < m; p += 256) {
    float4 rec = staged[sbase + p];
    unsigned int u = (unsigned int)__float_as_int(rec.w);
    int d = (int)(u >> 16) - n0;
    int pos = atomicAdd(&cur[d], 1);
    atomicAdd(&sX[d], rec.x);
    atomicAdd(&sY[d], rec.y);
    atomicAdd(&sZ[d], rec.z);
    rec.w = __int_as_float((int)(u & 0xffffu) * 256);
    e4[pos] = rec;
  }
  __syncthreads();
  if (t < nn) {
    int beg = begS[t], last = cur[t];  // cur == self-loop slot after placement
    float invc = 1.0f / fmaxf((float)(last - beg), 1.0f);
    float4 r;
    r.x = sX[t] * invc;
    r.y = sY[t] * invc;
    r.z = sZ[t] * invc;
    r.w = __int_as_float((n0 + t) * 256);
    e4[last] = r;
  }
}

// ---------------- merged MFMA GEMM: xl AND xr in one pass ----------------
// A = W in fragment-packed layout (coalesced lane*16B loads). B = x:
//   layer 0 reads f32 x_in rows (+in-register RNE convert);
//   layers 1,2 read xpack (fragment-packed by k_agg's epilogue) coalesced.
// Stores via per-wave LDS transpose -> 4x dwordx4 coalesced per matrix.
template <bool F32IN>
__global__ __launch_bounds__(256) void k_gemm_fused(const float* __restrict__ xf,
                                                    const unsigned short* __restrict__ xpack,
                                                    const unsigned short* __restrict__ Wb,
                                                    const float* __restrict__ bl,
                                                    const float* __restrict__ br,
                                                    unsigned short* __restrict__ xlb,
                                                    unsigned short* __restrict__ xrb, int N) {
  __shared__ unsigned short sld[4][2048];  // per-wave 16 nodes x 128ch
  int wave = threadIdx.x >> 6;
  int lane = threadIdx.x & 63;
  const unsigned short* WL = Wb;
  const unsigned short* WR = Wb + 16384;

  int row0 = (blockIdx.x * 4 + wave) * 16;
  if (row0 >= N) return;
  int m = lane & 15;
  int q = lane >> 4;

  bf16x8 bfrag[4];
  if constexpr (F32IN) {
    int brow = row0 + m;
    if (brow >= N) brow = N - 1;
    const float* xrow = xf + (size_t)brow * 128 + q * 8;
#pragma unroll
    for (int kt = 0; kt < 4; ++kt) {
      float4 u0 = *(const float4*)(xrow + kt * 32);
      float4 u1 = *(const float4*)(xrow + kt * 32 + 4);
      bf16x8 f;
      f[0] = (short)f2bf(u0.x); f[1] = (short)f2bf(u0.y);
      f[2] = (short)f2bf(u0.z); f[3] = (short)f2bf(u0.w);
      f[4] = (short)f2bf(u1.x); f[5] = (short)f2bf(u1.y);
      f[6] = (short)f2bf(u1.z); f[7] = (short)f2bf(u1.w);
      bfrag[kt] = f;
    }
  } else {
    const unsigned short* xrow = xpack + (size_t)(row0 >> 4) * 2048 + lane * 8;
#pragma unroll
    for (int kt = 0; kt < 4; ++kt) bfrag[kt] = *(const bf16x8*)(xrow + kt * 512);
  }

  f32x4 accL[8], accR[8];
#pragma unroll
  for (int jt = 0; jt < 8; ++jt) {
    accL[jt] = (f32x4){0.f, 0.f, 0.f, 0.f};
    accR[jt] = (f32x4){0.f, 0.f, 0.f, 0.f};
  }

#pragma unroll
  for (int kt = 0; kt < 4; ++kt) {
#pragma unroll
    for (int jt = 0; jt < 8; ++jt) {
      bf16x8 aL = *(const bf16x8*)(WL + (size_t)(jt * 4 + kt) * 512 + lane * 8);
      accL[jt] = __builtin_amdgcn_mfma_f32_16x16x32_bf16(aL, bfrag[kt], accL[jt], 0, 0, 0);
      bf16x8 aR = *(const bf16x8*)(WR + (size_t)(jt * 4 + kt) * 512 + lane * 8);
      accR[jt] = __builtin_amdgcn_mfma_f32_16x16x32_bf16(aR, bfrag[kt], accR[jt], 0, 0, 0);
    }
  }

  // ---- L: pack+bias -> LDS transpose -> coalesced stores ----
#pragma unroll
  for (int jt = 0; jt < 8; ++jt) {
    float4 bs = *(const float4*)&bl[jt * 16 + q * 4];
    uint2 p;
    p.x = (unsigned int)f2bf(accL[jt][0] + bs.x) | ((unsigned int)f2bf(accL[jt][1] + bs.y) << 16);
    p.y = (unsigned int)f2bf(accL[jt][2] + bs.z) | ((unsigned int)f2bf(accL[jt][3] + bs.w) << 16);
    *(uint2*)&sld[wave][m * 128 + jt * 16 + q * 4] = p;
  }
#pragma unroll
  for (int r = 0; r < 4; ++r) {
    uint4 vv = *(const uint4*)&sld[wave][r * 512 + lane * 8];
    int node = row0 + r * 4 + (lane >> 4);
    if (node < N) *(uint4*)(xlb + (size_t)row0 * 128 + r * 512 + lane * 8) = vv;
  }
  // ---- R: reuse LDS ----
#pragma unroll
  for (int jt = 0; jt < 8; ++jt) {
    float4 bs = *(const float4*)&br[jt * 16 + q * 4];
    uint2 p;
    p.x = (unsigned int)f2bf(accR[jt][0] + bs.x) | ((unsigned int)f2bf(accR[jt][1] + bs.y) << 16);
    p.y = (unsigned int)f2bf(accR[jt][2] + bs.z) | ((unsigned int)f2bf(accR[jt][3] + bs.w) << 16);
    *(uint2*)&sld[wave][m * 128 + jt * 16 + q * 4] = p;
  }
#pragma unroll
  for (int r = 0; r < 4; ++r) {
    uint4 vv = *(const uint4*)&sld[wave][r * 512 + lane * 8];
    int node = row0 + r * 4 + (lane >> 4);
    if (node < N) *(uint4*)(xrb + (size_t)row0 * 128 + r * 512 + lane * 8) = vv;
  }
}

// ---------------- fused: score + softmax(exp2) + weighted agg + epilogue ----------------
// one wave per node; lanes 0-31 = edge p, lanes 32-63 = edge p+1 (same node);
// each lane owns 4 channels c = (lane&31)*4; head group = 8 lanes.
// (R15 version verbatim -- proven best; loop frozen.)
__global__ __launch_bounds__(256) void k_agg(const unsigned short* __restrict__ xlb,
                                             const unsigned short* __restrict__ xrb,
                                             const float4* __restrict__ e4,
                                             const int* __restrict__ offs,
                                             const float* __restrict__ scoreTab,
                                             const float* __restrict__ bo,
                                             const float* __restrict__ lng, const float* __restrict__ lnb,
                                             unsigned short* __restrict__ xnext_pack,
                                             float* __restrict__ emb, int last, int N) {
  int w = (blockIdx.x * blockDim.x + threadIdx.x) >> 6;
  if (w >= N) return;
  int lane = threadIdx.x & 63;
  int half = lane >> 5;
  int sl = lane & 31;
  int c = sl * 4;
  unsigned int c2 = (unsigned int)(c * 2);  // byte offset into bf16 row
  int beg = offs[w], end = offs[w + 1];
  int cnt = end - beg;

  // packed per-lane params as float2 halves (channels 01 / 23)
  f32x2 xr01, xr23, wea01, wea23, web01, web23, wec01, wec23, at01, at23;
  {
    const float4* tp = (const float4*)(scoreTab + (size_t)sl * 16);
    float4 pa = tp[0], pb = tp[1], pc = tp[2], pt = tp[3];
    wea01[0] = pa.x; wea01[1] = pa.y; wea23[0] = pa.z; wea23[1] = pa.w;
    web01[0] = pb.x; web01[1] = pb.y; web23[0] = pb.z; web23[1] = pb.w;
    wec01[0] = pc.x; wec01[1] = pc.y; wec23[0] = pc.z; wec23[1] = pc.w;
    at01[0] = pt.x; at01[1] = pt.y; at23[0] = pt.z; at23[1] = pt.w;
    uint2 vr = *(const uint2*)&xrb[(size_t)w * 128 + c];
    xr01[0] = __uint_as_float(vr.x << 16);
    xr01[1] = __uint_as_float(vr.x & 0xffff0000u);
    xr23[0] = __uint_as_float(vr.y << 16);
    xr23[1] = __uint_as_float(vr.y & 0xffff0000u);
  }

  const char* e4B = (const char*)e4;
  const char* xlB = (const char*)xlb;

  float l = 0.f;
  f32x2 acc01 = {0.f, 0.f}, acc23 = {0.f, 0.f};

  unsigned int lastoff = (unsigned int)(end - 1) << 4;
  int T = (cnt + 1) >> 1;  // pair iterations

  // ---- pipeline prologue: records for pairs 0..2, gathers for pairs 0..1 ----
  unsigned int o0 = (unsigned int)(beg + half) << 4;
  if (o0 > lastoff) o0 = lastoff;  // cnt==1, half 1 clamps
  unsigned int o1 = o0 + 32u;
  if (o1 > lastoff) o1 = lastoff;
  unsigned int o2 = o1 + 32u;
  if (o2 > lastoff) o2 = lastoff;
  float4 e0 = *(const float4*)(e4B + o0);
  float4 e1 = *(const float4*)(e4B + o1);
  float4 e2 = *(const float4*)(e4B + o2);
  uint2 g0 = *(const uint2*)(xlB + ((unsigned int)__float_as_int(e0.w) + c2));
  uint2 g1 = *(const uint2*)(xlB + ((unsigned int)__float_as_int(e1.w) + c2));
  unsigned int offP = o2;

  // one edge: unpack gather, score (packed f32), exp2, accumulate.
  auto compute = [&](const float4& e, uint2 v, bool valid) {
    f32x2 xl01, xl23;
    xl01[0] = __uint_as_float(v.x << 16);
    xl01[1] = __uint_as_float(v.x & 0xffff0000u);
    xl23[0] = __uint_as_float(v.y << 16);
    xl23[1] = __uint_as_float(v.y & 0xffff0000u);
    f32x2 ex = {e.x, e.x}, ey = {e.y, e.y}, ez = {e.z, e.z};
    f32x2 t01 = __builtin_elementwise_fma(wea01, ex,
                  __builtin_elementwise_fma(web01, ey,
                    __builtin_elementwise_fma(wec01, ez, xr01 + xl01)));
    f32x2 t23 = __builtin_elementwise_fma(wea23, ex,
                  __builtin_elementwise_fma(web23, ey,
                    __builtin_elementwise_fma(wec23, ez, xr23 + xl23)));
    t01 = __builtin_elementwise_max(t01, t01 * 0.2f);
    t23 = __builtin_elementwise_max(t23, t23 * 0.2f);
    f32x2 d2 = __builtin_elementwise_fma(t01, at01, t23 * at23);
    float s = d2[0] + d2[1];
    float wgt = __builtin_amdgcn_exp2f(dpp_sum8(s));
    if (!valid) wgt = 0.f;
    l += wgt;
    f32x2 w2 = {wgt, wgt};
    acc01 = __builtin_elementwise_fma(xl01, w2, acc01);
    acc23 = __builtin_elementwise_fma(xl23, w2, acc23);
  };

  // ---- steady state: record(i+3), gather(i+2), compute(i) ----
#pragma unroll 2
  for (int it = 0; it < T - 3; ++it) {
    unsigned int o3 = offP + 32u;
    if (o3 > lastoff) o3 = lastoff;
    float4 e3 = *(const float4*)(e4B + o3);
    uint2 g2 = *(const uint2*)(xlB + ((unsigned int)__float_as_int(e2.w) + c2));
    compute(e0, g0, true);
    e0 = e1; e1 = e2; e2 = e3;
    g0 = g1; g1 = g2;
    offP = o3;
  }
  if (T >= 3) {  // pair T-3: issue last gather, compute
    uint2 g2 = *(const uint2*)(xlB + ((unsigned int)__float_as_int(e2.w) + c2));
    compute(e0, g0, true);
    e0 = e1; e1 = e2;
    g0 = g1; g1 = g2;
  }
  if (T >= 2) {  // pair T-2 (always fully valid)
    compute(e0, g0, true);
    e0 = e1;
    g0 = g1;
  }
  {  // pair T-1 (masked: odd cnt leaves half==1 invalid)
    int idx = 2 * (T - 1) + half;
    compute(e0, g0, idx < cnt);
  }

  // combine halves
  l += __shfl_xor(l, 32);
  float a0 = acc01[0]; a0 += __shfl_xor(a0, 32);
  float a1 = acc01[1]; a1 += __shfl_xor(a1, 32);
  float a2 = acc23[0]; a2 += __shfl_xor(a2, 32);
  float a3 = acc23[1]; a3 += __shfl_xor(a3, 32);

  float inv = 1.0f / l;
  f32x4 o4;
  const float4 bo4 = *(const float4*)&bo[c];
  o4[0] = a0 * inv + bo4.x;
  o4[1] = a1 * inv + bo4.y;
  o4[2] = a2 * inv + bo4.z;
  o4[3] = a3 * inv + bo4.w;

  if (last) {
    if (half == 0) {
      float4 st = {o4[0], o4[1], o4[2], o4[3]};
      *(float4*)&emb[(size_t)w * 128 + c] = st;
    }
  } else {
    f32x4 r;
    r[0] = fmaxf(o4[0], 0.f);
    r[1] = fmaxf(o4[1], 0.f);
    r[2] = fmaxf(o4[2], 0.f);
    r[3] = fmaxf(o4[3], 0.f);
    float s = r[0] + r[1] + r[2] + r[3];
    s += __shfl_xor(s, 1);
    s += __shfl_xor(s, 2);
    s += __shfl_xor(s, 4);
    s += __shfl_xor(s, 8);
    s += __shfl_xor(s, 16);
    float mu = s * 0.0078125f;  // /128
    f32x4 d;
    d[0] = r[0] - mu;
    d[1] = r[1] - mu;
    d[2] = r[2] - mu;
    d[3] = r[3] - mu;
    float v2 = d[0] * d[0] + d[1] * d[1] + d[2] * d[2] + d[3] * d[3];
    v2 += __shfl_xor(v2, 1);
    v2 += __shfl_xor(v2, 2);
    v2 += __shfl_xor(v2, 4);
    v2 += __shfl_xor(v2, 8);
    v2 += __shfl_xor(v2, 16);
    float var = v2 * 0.0078125f;
    float rstd = rsqrtf(var + LN_EPS);
    if (half == 0) {
      const float4 g4 = *(const float4*)&lng[c];
      const float4 b4 = *(const float4*)&lnb[c];
      float o0 = d[0] * rstd * g4.x + b4.x;
      float o1 = d[1] * rstd * g4.y + b4.y;
      float o2 = d[2] * rstd * g4.z + b4.z;
      float o3 = d[3] * rstd * g4.w + b4.w;
      uint2 pack;
      pack.x = (unsigned int)f2bf(o0) | ((unsigned int)f2bf(o1) << 16);
      pack.y = (unsigned int)f2bf(o2) | ((unsigned int)f2bf(o3) << 16);
      // fragment-packed write: node w -> block B=w>>4, m=w&15;
      // channels c..c+3: kt=sl>>3, q=(sl>>1)&3, half8=(sl&1)*4
      int kt = sl >> 3;
      int qq = (sl >> 1) & 3;
      size_t elem = (size_t)(w >> 4) * 2048 + kt * 512 + (qq * 16 + (w & 15)) * 8 + (sl & 1) * 4;
      *(uint2*)&xnext_pack[elem] = pack;
    }
  }
}

// ---------------- graph max-pool (relu implicit: atomicMax vs 0-init) ----------------
__global__ void k_pool(const float* __restrict__ emb, const int* __restrict__ batch,
                       float* __restrict__ pooled, int N) {
  int c = threadIdx.x & 127;
  int half = threadIdx.x >> 7;
  int base = blockIdx.x * 64 + half;
  int limit = min(blockIdx.x * 64 + 64, N);
  float cur = 0.f;
  int curg = -1;
  for (int n = base; n < limit; n += 2) {
    int g = batch[n];
    if (g != curg) {
      if (curg >= 0) atomicMax((unsigned int*)&pooled[curg * 128 + c], __float_as_uint(cur));
      curg = g;
      cur = 0.f;
    }
    cur = fmaxf(cur, emb[(size_t)n * 128 + c]);
  }
  if (curg >= 0) atomicMax((unsigned int*)&pooled[curg * 128 + c], __float_as_uint(cur));
}

// ---------------- MLP: 128 -> 32 -> 32 -> 32 -> 1 ----------------
__global__ void k_mlp(const float* __restrict__ pooled,
                      const float* __restrict__ pw1, const float* __restrict__ pb1,
                      const float* __restrict__ pw2, const float* __restrict__ pb2,
                      const float* __restrict__ pw3, const float* __restrict__ pb3,
                      const float* __restrict__ pw4, const float* __restrict__ pb4,
                      float* __restrict__ out) {
  int g = blockIdx.x;
  int t = threadIdx.x;  // 64 threads
  __shared__ float buf1[32], buf2[32];
  if (t < 32) {
    float acc = pb1[t];
    for (int k = 0; k < 128; ++k) acc += pw1[t * 128 + k] * pooled[g * 128 + k];
    buf1[t] = fmaxf(acc, 0.f);
  }
  __syncthreads();
  if (t < 32) {
    float acc = pb2[t];
    for (int k = 0; k < 32; ++k) acc += pw2[t * 32 + k] * buf1[k];
    buf2[t] = fmaxf(acc, 0.f);
  }
  __syncthreads();
  if (t < 32) {
    float acc = pb3[t];
    for (int k = 0; k < 32; ++k) acc += pw3[t * 32 + k] * buf2[k];
    buf1[t] = fmaxf(acc, 0.f);
  }
  __syncthreads();
  if (t == 0) {
    float acc = pb4[0];
    for (int k = 0; k < 32; ++k) acc += pw4[k] * buf1[k];
    out[g] = acc;
  }
}

// ---------------------------------------------------------------------------

extern "C" void kernel_launch(void* const* d_in, const int* in_sizes, int n_in,
                              void* d_out, int out_size, void* d_ws, size_t ws_size,
                              hipStream_t stream) {
  const float* x_in = (const float*)d_in[0];
  const int* ei = (const int*)d_in[1];
  const int* batch = (const int*)d_in[2];
  const float* ea = (const float*)d_in[3];

  const int N = in_sizes[0] / 128;
  const int E = in_sizes[1] / 2;
  const int EP = E + N;
  const int G = out_size - N * 128;
  const int NBUK = (N + 255) / 256;
  const int NBINA = (E + CHUNK - 1) / CHUNK;

  const float *Wl[3], *bl[3], *Wr[3], *br[3], *We[3], *att[3], *bo[3];
  for (int l = 0; l < 3; ++l) {
    Wl[l] = (const float*)d_in[4 + 7 * l];
    bl[l] = (const float*)d_in[5 + 7 * l];
    Wr[l] = (const float*)d_in[6 + 7 * l];
    br[l] = (const float*)d_in[7 + 7 * l];
    We[l] = (const float*)d_in[8 + 7 * l];
    att[l] = (const float*)d_in[9 + 7 * l];
    bo[l] = (const float*)d_in[10 + 7 * l];
  }
  const float* lng[2] = {(const float*)d_in[25], (const float*)d_in[27]};
  const float* lnb[2] = {(const float*)d_in[26], (const float*)d_in[28]};
  const float* pw1 = (const float*)d_in[29];
  const float* pb1 = (const float*)d_in[30];
  const float* pw2 = (const float*)d_in[31];
  const float* pb2 = (const float*)d_in[32];
  const float* pw3 = (const float*)d_in[33];
  const float* pb3 = (const float*)d_in[34];
  const float* pw4 = (const float*)d_in[35];
  const float* pb4 = (const float*)d_in[36];

  char* base = (char*)d_ws;
  size_t cur = 0;
  auto carve = [&](size_t bytes) -> char* {
    char* p = base + cur;
    cur += (bytes + 255) & ~(size_t)255;
    return p;
  };
  unsigned short* xlb = (unsigned short*)carve((size_t)N * 128 * 2);
  unsigned short* xrb = (unsigned short*)carve((size_t)N * 128 * 2);
  // xpack: fragment-packed inter-layer activations; +1 block slack for tail
  unsigned short* xpack = (unsigned short*)carve(((size_t)((N + 15) / 16) + 1) * 2048 * 2);
  unsigned short* Wb = (unsigned short*)carve((size_t)6 * 16384 * 2);
  float4* e4 = (float4*)carve((size_t)(EP + 8) * 16);  // +8 pad records
  float4* staged = (float4*)carve((size_t)NBUK * BCAP * 16);
  int* offs = (int*)carve((size_t)(N + 1) * 4);
  int* gcnt = (int*)carve((size_t)NBUK * 4);
  float* scoreTab = (float*)carve((size_t)3 * 512 * 4);
  float* pooled = (float*)carve((size_t)G * 128 * 4);

  float* emb_out = (float*)d_out;
  float* mlp_out = (float*)d_out + (size_t)N * 128;

  hipMemsetAsync(gcnt, 0, (size_t)NBUK * 4, stream);
  hipMemsetAsync(pooled, 0, (size_t)G * 128 * 4, stream);

  // packed prologue: binA blocks + packed-convW blocks + 1 pack block
  k_pre<<<NBINA + 48 + 1, 256, 0, stream>>>(ei, ea, gcnt, staged, E, NBUK, NBINA,
                                            Wl[0], Wr[0], Wl[1], Wr[1], Wl[2], Wr[2], Wb,
                                            We[0], att[0], We[1], att[1], We[2], att[2],
                                            scoreTab);
  k_binB<<<NBUK, 256, 0, stream>>>(staged, gcnt, e4, offs, N, NBUK, EP);

  for (int l = 0; l < 3; ++l) {
    dim3 ggrid((N + 63) / 64);
    if (l == 0) {
      k_gemm_fused<true><<<ggrid, 256, 0, stream>>>(x_in, xpack, Wb, bl[0], br[0], xlb, xrb, N);
    } else {
      k_gemm_fused<false><<<ggrid, 256, 0, stream>>>(nullptr, xpack, Wb + (size_t)l * 32768,
                                                     bl[l], br[l], xlb, xrb, N);
    }
    int last = (l == 2) ? 1 : 0;
    const float* g = last ? bo[l] : lng[l];
    const float* b = last ? bo[l] : lnb[l];
    k_agg<<<(N * 64 + 255) / 256, 256, 0, stream>>>(xlb, xrb, e4, offs,
                                                    scoreTab + (size_t)l * 512,
                                                    bo[l], g, b,
                                                    xpack, emb_out, last, N);
  }

  k_pool<<<(N + 63) / 64, 256, 0, stream>>>(emb_out, batch, pooled, N);
  k_mlp<<<G, 64, 0, stream>>>(pooled, pw1, pb1, pw2, pb2, pw3, pb3, pw4, pb4, mlp_out);
}

// Round 11
// 466.679 us; speedup vs baseline: 1.0287x; 1.0120x over previous
//
#include <hip/hip_runtime.h>
#include <math.h>

// ---------------------------------------------------------------------------
// GATv2 x3 + LN + graph max-pool + MLP.
// Round 20: k_binB thread count 256 -> 512 (8 waves/block). Timestamp
// accounting (R19) showed the 282us non-agg time is REAL kernel time, not
// harness overhead; k_binB runs 196 blocks x 4 waves = 784 waves on 1024
// SIMDs (<1/SIMD, 60 CUs idle) -- latency-bound scattered-write work with
// zero TLP cover. Same algorithm: scans guarded to t<256 (all-thread
// barriers), record loops stride 512. Everything else R19-verbatim;
// k_agg frozen (R15 loop, 6 structural attempts all neutral-to-worse).
// ---------------------------------------------------------------------------

#define LN_EPS 1e-5f
#define LOG2E 1.44269504088896340736f
#define CHUNK 2048
#define BCAP 8192  // records per staging bucket (avg 4096)

typedef short bf16x8 __attribute__((ext_vector_type(8)));
typedef float f32x4 __attribute__((ext_vector_type(4)));
typedef float f32x2 __attribute__((ext_vector_type(2)));

static __device__ __forceinline__ unsigned short f2bf(float f) {
  unsigned int u = __float_as_uint(f);
  u += 0x7fffu + ((u >> 16) & 1u);  // RNE
  return (unsigned short)(u >> 16);
}

// sum+broadcast over each 8-lane group: quad xor1, quad xor2, row_half_mirror
static __device__ __forceinline__ float dpp_sum8(float v) {
  int x;
  x = __builtin_amdgcn_update_dpp(0, __float_as_int(v), 0x0B1, 0xf, 0xf, true);  // quad_perm 1,0,3,2
  v += __int_as_float(x);
  x = __builtin_amdgcn_update_dpp(0, __float_as_int(v), 0x04E, 0xf, 0xf, true);  // quad_perm 2,3,0,1
  v += __int_as_float(x);
  x = __builtin_amdgcn_update_dpp(0, __float_as_int(v), 0x141, 0xf, 0xf, true);  // row_half_mirror
  v += __int_as_float(x);
  return v;
}

// ---------------- packed prologue: {binA | convW(packed) | pack} ----------------
// W fragment layout per matrix (16384 ushorts):
//   chunk c in [0,2048): lane=c&63, kt=(c>>6)&3, jt=c>>8
//   Wp[c*8+j] = W[(jt*16 + (lane&15))*128 + kt*32 + (lane>>4)*8 + j]
__global__ __launch_bounds__(256) void k_pre(
    const int* __restrict__ ei, const float* __restrict__ ea,
    int* __restrict__ gcnt, float4* __restrict__ staged, int E, int nbuk, int nbinA,
    const float* __restrict__ w0, const float* __restrict__ w1,
    const float* __restrict__ w2, const float* __restrict__ w3,
    const float* __restrict__ w4, const float* __restrict__ w5,
    unsigned short* __restrict__ Wb,
    const float* __restrict__ We0, const float* __restrict__ att0,
    const float* __restrict__ We1, const float* __restrict__ att1,
    const float* __restrict__ We2, const float* __restrict__ att2,
    float* __restrict__ tab) {
  __shared__ int hist[256];
  __shared__ int basebuf[256];
  int b = blockIdx.x;
  int t = threadIdx.x;

  if (b < nbinA) {
    // ---- binA: histogram edges into 256-node buckets, stage records ----
    int e0 = b * CHUNK;
    hist[t] = 0;
    __syncthreads();
#pragma unroll
    for (int i = 0; i < CHUNK / 256; ++i) {
      int e = e0 + i * 256 + t;
      if (e < E) atomicAdd(&hist[ei[E + e] >> 8], 1);
    }
    __syncthreads();
    int h = hist[t];
    if (t < nbuk && h > 0) basebuf[t] = t * BCAP + atomicAdd(&gcnt[t], h);
    hist[t] = 0;
    __syncthreads();
#pragma unroll
    for (int i = 0; i < CHUNK / 256; ++i) {
      int e = e0 + i * 256 + t;
      if (e < E) {
        int s = ei[e];
        int d = ei[E + e];
        int bk = d >> 8;
        int r = atomicAdd(&hist[bk], 1);
        float4 rec;
        rec.x = ea[e * 3 + 0];
        rec.y = ea[e * 3 + 1];
        rec.z = ea[e * 3 + 2];
        rec.w = __int_as_float(s | (d << 16));
        staged[basebuf[bk] + r] = rec;
      }
    }
  } else if (b < nbinA + 48) {
    // ---- convW packed: 6 matrices x 8 blocks; thread does one 8-elem chunk ----
    int bb = b - nbinA;
    const float* srcs[6] = {w0, w1, w2, w3, w4, w5};
    int mtx = bb >> 3;
    int c = (bb & 7) * 256 + t;  // chunk in [0,2048)
    int lane = c & 63;
    int kt = (c >> 6) & 3;
    int jt = c >> 8;
    const float* s = srcs[mtx] + (size_t)(jt * 16 + (lane & 15)) * 128 + kt * 32 + (lane >> 4) * 8;
    unsigned short* d = Wb + (size_t)mtx * 16384 + (size_t)c * 8;
#pragma unroll
    for (int j = 0; j < 8; ++j) d[j] = f2bf(s[j]);
  } else {
    // ---- pack: per-layer, per-lane score params ----
    if (t < 96) {
      int l = t >> 5;
      int sl = t & 31;
      const float* We = (l == 0) ? We0 : ((l == 1) ? We1 : We2);
      const float* att = (l == 0) ? att0 : ((l == 1) ? att1 : att2);
      float* o = tab + (size_t)l * 512 + sl * 16;
#pragma unroll
      for (int j = 0; j < 4; ++j) {
        o[j] = We[(sl * 4 + j) * 3 + 0];
        o[4 + j] = We[(sl * 4 + j) * 3 + 1];
        o[8 + j] = We[(sl * 4 + j) * 3 + 2];
        o[12 + j] = att[sl * 4 + j] * LOG2E;
      }
    }
  }
}

// ---------------- binB + folded bucket-prefix scan + LDS attr sums ----------------
// R20: 512 threads (8 waves/block) for TLP cover on the scattered e4 writes;
// scans remain 256-wide (t<256 guarded, all-thread barriers).
__global__ __launch_bounds__(512) void k_binB(const float4* __restrict__ staged,
                                              const int* __restrict__ gcnt,
                                              float4* __restrict__ e4,
                                              int* __restrict__ offs, int N, int nbuk, int EP) {
  __shared__ int hist[256], cur[256], begS[256], sh[256];
  __shared__ float sX[256], sY[256], sZ[256];
  int t = threadIdx.x;
  int b = blockIdx.x;
  int n0 = b * 256;
  int nn = min(256, N - n0);
  int m = gcnt[b];
  size_t sbase = (size_t)b * BCAP;

  // ---- global bucket prefix (each block computes locally; removes k_bscan) ----
  if (t < 256) {
    int nodes_t = (t < nbuk) ? min(256, N - t * 256) : 0;
    sh[t] = (t < nbuk) ? gcnt[t] + nodes_t : 0;
  }
  __syncthreads();
  for (int d = 1; d < 256; d <<= 1) {
    int add = (t >= d && t < 256) ? sh[t - d] : 0;
    __syncthreads();
    if (t < 256) sh[t] += add;
    __syncthreads();
  }
  int bukStart_b = (b == 0) ? 0 : sh[b - 1];
  if (b == 0) {
    if (t == 0) offs[N] = EP;
    if (t < 8) {  // pad records: valid gather offset (row 0), finite attrs
      float4 r;
      r.x = 0.f; r.y = 0.f; r.z = 0.f;
      r.w = __int_as_float(0);
      e4[EP + t] = r;
    }
  }
  __syncthreads();

  // ---- per-node histogram within bucket ----
  if (t < 256) {
    hist[t] = 0;
    sX[t] = 0.f; sY[t] = 0.f; sZ[t] = 0.f;
  }
  __syncthreads();
  for (int p = t; p < m; p += 512) {
    unsigned int u = (unsigned int)__float_as_int(staged[sbase + p].w);
    atomicAdd(&hist[(int)(u >> 16) - n0], 1);
  }
  __syncthreads();
  int v = (t < nn) ? hist[t] + 1 : 0;
  if (t < 256) sh[t] = v;
  __syncthreads();
  for (int d = 1; d < 256; d <<= 1) {
    int add = (t >= d && t < 256) ? sh[t - d] : 0;
    __syncthreads();
    if (t < 256) sh[t] += add;
    __syncthreads();
  }
  if (t < nn) {
    int base = bukStart_b + sh[t] - v;
    cur[t] = base;
    begS[t] = base;
    offs[n0 + t] = base;
  }
  __syncthreads();
  // ---- placement + attr sums (LDS atomics) ----
  for (int p = t; p < m; p += 512) {
    float4 rec = staged[sbase + p];
    unsigned int u = (unsigned int)__float_as_int(rec.w);
    int d = (int)(u >> 16) - n0;
    int pos = atomicAdd(&cur[d], 1);
    atomicAdd(&sX[d], rec.x);
    atomicAdd(&sY[d], rec.y);
    atomicAdd(&sZ[d], rec.z);
    rec.w = __int_as_float((int)(u & 0xffffu) * 256);
    e4[pos] = rec;
  }
  __syncthreads();
  if (t < nn) {
    int beg = begS[t], last = cur[t];  // cur == self-loop slot after placement
    float invc = 1.0f / fmaxf((float)(last - beg), 1.0f);
    float4 r;
    r.x = sX[t] * invc;
    r.y = sY[t] * invc;
    r.z = sZ[t] * invc;
    r.w = __int_as_float((n0 + t) * 256);
    e4[last] = r;
  }
}

// ---------------- merged MFMA GEMM: xl AND xr in one pass ----------------
// A = W in fragment-packed layout (coalesced lane*16B loads). B = x:
//   layer 0 reads f32 x_in rows (+in-register RNE convert);
//   layers 1,2 read xpack (fragment-packed by k_agg's epilogue) coalesced.
// Stores via per-wave LDS transpose -> 4x dwordx4 coalesced per matrix.
template <bool F32IN>
__global__ __launch_bounds__(256) void k_gemm_fused(const float* __restrict__ xf,
                                                    const unsigned short* __restrict__ xpack,
                                                    const unsigned short* __restrict__ Wb,
                                                    const float* __restrict__ bl,
                                                    const float* __restrict__ br,
                                                    unsigned short* __restrict__ xlb,
                                                    unsigned short* __restrict__ xrb, int N) {
  __shared__ unsigned short sld[4][2048];  // per-wave 16 nodes x 128ch
  int wave = threadIdx.x >> 6;
  int lane = threadIdx.x & 63;
  const unsigned short* WL = Wb;
  const unsigned short* WR = Wb + 16384;

  int row0 = (blockIdx.x * 4 + wave) * 16;
  if (row0 >= N) return;
  int m = lane & 15;
  int q = lane >> 4;

  bf16x8 bfrag[4];
  if constexpr (F32IN) {
    int brow = row0 + m;
    if (brow >= N) brow = N - 1;
    const float* xrow = xf + (size_t)brow * 128 + q * 8;
#pragma unroll
    for (int kt = 0; kt < 4; ++kt) {
      float4 u0 = *(const float4*)(xrow + kt * 32);
      float4 u1 = *(const float4*)(xrow + kt * 32 + 4);
      bf16x8 f;
      f[0] = (short)f2bf(u0.x); f[1] = (short)f2bf(u0.y);
      f[2] = (short)f2bf(u0.z); f[3] = (short)f2bf(u0.w);
      f[4] = (short)f2bf(u1.x); f[5] = (short)f2bf(u1.y);
      f[6] = (short)f2bf(u1.z); f[7] = (short)f2bf(u1.w);
      bfrag[kt] = f;
    }
  } else {
    const unsigned short* xrow = xpack + (size_t)(row0 >> 4) * 2048 + lane * 8;
#pragma unroll
    for (int kt = 0; kt < 4; ++kt) bfrag[kt] = *(const bf16x8*)(xrow + kt * 512);
  }

  f32x4 accL[8], accR[8];
#pragma unroll
  for (int jt = 0; jt < 8; ++jt) {
    accL[jt] = (f32x4){0.f, 0.f, 0.f, 0.f};
    accR[jt] = (f32x4){0.f, 0.f, 0.f, 0.f};
  }

#pragma unroll
  for (int kt = 0; kt < 4; ++kt) {
#pragma unroll
    for (int jt = 0; jt < 8; ++jt) {
      bf16x8 aL = *(const bf16x8*)(WL + (size_t)(jt * 4 + kt) * 512 + lane * 8);
      accL[jt] = __builtin_amdgcn_mfma_f32_16x16x32_bf16(aL, bfrag[kt], accL[jt], 0, 0, 0);
      bf16x8 aR = *(const bf16x8*)(WR + (size_t)(jt * 4 + kt) * 512 + lane * 8);
      accR[jt] = __builtin_amdgcn_mfma_f32_16x16x32_bf16(aR, bfrag[kt], accR[jt], 0, 0, 0);
    }
  }

  // ---- L: pack+bias -> LDS transpose -> coalesced stores ----
#pragma unroll
  for (int jt = 0; jt < 8; ++jt) {
    float4 bs = *(const float4*)&bl[jt * 16 + q * 4];
    uint2 p;
    p.x = (unsigned int)f2bf(accL[jt][0] + bs.x) | ((unsigned int)f2bf(accL[jt][1] + bs.y) << 16);
    p.y = (unsigned int)f2bf(accL[jt][2] + bs.z) | ((unsigned int)f2bf(accL[jt][3] + bs.w) << 16);
    *(uint2*)&sld[wave][m * 128 + jt * 16 + q * 4] = p;
  }
#pragma unroll
  for (int r = 0; r < 4; ++r) {
    uint4 vv = *(const uint4*)&sld[wave][r * 512 + lane * 8];
    int node = row0 + r * 4 + (lane >> 4);
    if (node < N) *(uint4*)(xlb + (size_t)row0 * 128 + r * 512 + lane * 8) = vv;
  }
  // ---- R: reuse LDS ----
#pragma unroll
  for (int jt = 0; jt < 8; ++jt) {
    float4 bs = *(const float4*)&br[jt * 16 + q * 4];
    uint2 p;
    p.x = (unsigned int)f2bf(accR[jt][0] + bs.x) | ((unsigned int)f2bf(accR[jt][1] + bs.y) << 16);
    p.y = (unsigned int)f2bf(accR[jt][2] + bs.z) | ((unsigned int)f2bf(accR[jt][3] + bs.w) << 16);
    *(uint2*)&sld[wave][m * 128 + jt * 16 + q * 4] = p;
  }
#pragma unroll
  for (int r = 0; r < 4; ++r) {
    uint4 vv = *(const uint4*)&sld[wave][r * 512 + lane * 8];
    int node = row0 + r * 4 + (lane >> 4);
    if (node < N) *(uint4*)(xrb + (size_t)row0 * 128 + r * 512 + lane * 8) = vv;
  }
}

// ---------------- fused: score + softmax(exp2) + weighted agg + epilogue ----------------
// one wave per node; lanes 0-31 = edge p, lanes 32-63 = edge p+1 (same node);
// each lane owns 4 channels c = (lane&31)*4; head group = 8 lanes.
// (R15 version verbatim -- proven best; loop frozen.)
__global__ __launch_bounds__(256) void k_agg(const unsigned short* __restrict__ xlb,
                                             const unsigned short* __restrict__ xrb,
                                             const float4* __restrict__ e4,
                                             const int* __restrict__ offs,
                                             const float* __restrict__ scoreTab,
                                             const float* __restrict__ bo,
                                             const float* __restrict__ lng, const float* __restrict__ lnb,
                                             unsigned short* __restrict__ xnext_pack,
                                             float* __restrict__ emb, int last, int N) {
  int w = (blockIdx.x * blockDim.x + threadIdx.x) >> 6;
  if (w >= N) return;
  int lane = threadIdx.x & 63;
  int half = lane >> 5;
  int sl = lane & 31;
  int c = sl * 4;
  unsigned int c2 = (unsigned int)(c * 2);  // byte offset into bf16 row
  int beg = offs[w], end = offs[w + 1];
  int cnt = end - beg;

  // packed per-lane params as float2 halves (channels 01 / 23)
  f32x2 xr01, xr23, wea01, wea23, web01, web23, wec01, wec23, at01, at23;
  {
    const float4* tp = (const float4*)(scoreTab + (size_t)sl * 16);
    float4 pa = tp[0], pb = tp[1], pc = tp[2], pt = tp[3];
    wea01[0] = pa.x; wea01[1] = pa.y; wea23[0] = pa.z; wea23[1] = pa.w;
    web01[0] = pb.x; web01[1] = pb.y; web23[0] = pb.z; web23[1] = pb.w;
    wec01[0] = pc.x; wec01[1] = pc.y; wec23[0] = pc.z; wec23[1] = pc.w;
    at01[0] = pt.x; at01[1] = pt.y; at23[0] = pt.z; at23[1] = pt.w;
    uint2 vr = *(const uint2*)&xrb[(size_t)w * 128 + c];
    xr01[0] = __uint_as_float(vr.x << 16);
    xr01[1] = __uint_as_float(vr.x & 0xffff0000u);
    xr23[0] = __uint_as_float(vr.y << 16);
    xr23[1] = __uint_as_float(vr.y & 0xffff0000u);
  }

  const char* e4B = (const char*)e4;
  const char* xlB = (const char*)xlb;

  float l = 0.f;
  f32x2 acc01 = {0.f, 0.f}, acc23 = {0.f, 0.f};

  unsigned int lastoff = (unsigned int)(end - 1) << 4;
  int T = (cnt + 1) >> 1;  // pair iterations

  // ---- pipeline prologue: records for pairs 0..2, gathers for pairs 0..1 ----
  unsigned int o0 = (unsigned int)(beg + half) << 4;
  if (o0 > lastoff) o0 = lastoff;  // cnt==1, half 1 clamps
  unsigned int o1 = o0 + 32u;
  if (o1 > lastoff) o1 = lastoff;
  unsigned int o2 = o1 + 32u;
  if (o2 > lastoff) o2 = lastoff;
  float4 e0 = *(const float4*)(e4B + o0);
  float4 e1 = *(const float4*)(e4B + o1);
  float4 e2 = *(const float4*)(e4B + o2);
  uint2 g0 = *(const uint2*)(xlB + ((unsigned int)__float_as_int(e0.w) + c2));
  uint2 g1 = *(const uint2*)(xlB + ((unsigned int)__float_as_int(e1.w) + c2));
  unsigned int offP = o2;

  // one edge: unpack gather, score (packed f32), exp2, accumulate.
  auto compute = [&](const float4& e, uint2 v, bool valid) {
    f32x2 xl01, xl23;
    xl01[0] = __uint_as_float(v.x << 16);
    xl01[1] = __uint_as_float(v.x & 0xffff0000u);
    xl23[0] = __uint_as_float(v.y << 16);
    xl23[1] = __uint_as_float(v.y & 0xffff0000u);
    f32x2 ex = {e.x, e.x}, ey = {e.y, e.y}, ez = {e.z, e.z};
    f32x2 t01 = __builtin_elementwise_fma(wea01, ex,
                  __builtin_elementwise_fma(web01, ey,
                    __builtin_elementwise_fma(wec01, ez, xr01 + xl01)));
    f32x2 t23 = __builtin_elementwise_fma(wea23, ex,
                  __builtin_elementwise_fma(web23, ey,
                    __builtin_elementwise_fma(wec23, ez, xr23 + xl23)));
    t01 = __builtin_elementwise_max(t01, t01 * 0.2f);
    t23 = __builtin_elementwise_max(t23, t23 * 0.2f);
    f32x2 d2 = __builtin_elementwise_fma(t01, at01, t23 * at23);
    float s = d2[0] + d2[1];
    float wgt = __builtin_amdgcn_exp2f(dpp_sum8(s));
    if (!valid) wgt = 0.f;
    l += wgt;
    f32x2 w2 = {wgt, wgt};
    acc01 = __builtin_elementwise_fma(xl01, w2, acc01);
    acc23 = __builtin_elementwise_fma(xl23, w2, acc23);
  };

  // ---- steady state: record(i+3), gather(i+2), compute(i) ----
#pragma unroll 2
  for (int it = 0; it < T - 3; ++it) {
    unsigned int o3 = offP + 32u;
    if (o3 > lastoff) o3 = lastoff;
    float4 e3 = *(const float4*)(e4B + o3);
    uint2 g2 = *(const uint2*)(xlB + ((unsigned int)__float_as_int(e2.w) + c2));
    compute(e0, g0, true);
    e0 = e1; e1 = e2; e2 = e3;
    g0 = g1; g1 = g2;
    offP = o3;
  }
  if (T >= 3) {  // pair T-3: issue last gather, compute
    uint2 g2 = *(const uint2*)(xlB + ((unsigned int)__float_as_int(e2.w) + c2));
    compute(e0, g0, true);
    e0 = e1; e1 = e2;
    g0 = g1; g1 = g2;
  }
  if (T >= 2) {  // pair T-2 (always fully valid)
    compute(e0, g0, true);
    e0 = e1;
    g0 = g1;
  }
  {  // pair T-1 (masked: odd cnt leaves half==1 invalid)
    int idx = 2 * (T - 1) + half;
    compute(e0, g0, idx < cnt);
  }

  // combine halves
  l += __shfl_xor(l, 32);
  float a0 = acc01[0]; a0 += __shfl_xor(a0, 32);
  float a1 = acc01[1]; a1 += __shfl_xor(a1, 32);
  float a2 = acc23[0]; a2 += __shfl_xor(a2, 32);
  float a3 = acc23[1]; a3 += __shfl_xor(a3, 32);

  float inv = 1.0f / l;
  f32x4 o4;
  const float4 bo4 = *(const float4*)&bo[c];
  o4[0] = a0 * inv + bo4.x;
  o4[1] = a1 * inv + bo4.y;
  o4[2] = a2 * inv + bo4.z;
  o4[3] = a3 * inv + bo4.w;

  if (last) {
    if (half == 0) {
      float4 st = {o4[0], o4[1], o4[2], o4[3]};
      *(float4*)&emb[(size_t)w * 128 + c] = st;
    }
  } else {
    f32x4 r;
    r[0] = fmaxf(o4[0], 0.f);
    r[1] = fmaxf(o4[1], 0.f);
    r[2] = fmaxf(o4[2], 0.f);
    r[3] = fmaxf(o4[3], 0.f);
    float s = r[0] + r[1] + r[2] + r[3];
    s += __shfl_xor(s, 1);
    s += __shfl_xor(s, 2);
    s += __shfl_xor(s, 4);
    s += __shfl_xor(s, 8);
    s += __shfl_xor(s, 16);
    float mu = s * 0.0078125f;  // /128
    f32x4 d;
    d[0] = r[0] - mu;
    d[1] = r[1] - mu;
    d[2] = r[2] - mu;
    d[3] = r[3] - mu;
    float v2 = d[0] * d[0] + d[1] * d[1] + d[2] * d[2] + d[3] * d[3];
    v2 += __shfl_xor(v2, 1);
    v2 += __shfl_xor(v2, 2);
    v2 += __shfl_xor(v2, 4);
    v2 += __shfl_xor(v2, 8);
    v2 += __shfl_xor(v2, 16);
    float var = v2 * 0.0078125f;
    float rstd = rsqrtf(var + LN_EPS);
    if (half == 0) {
      const float4 g4 = *(const float4*)&lng[c];
      const float4 b4 = *(const float4*)&lnb[c];
      float o0 = d[0] * rstd * g4.x + b4.x;
      float o1 = d[1] * rstd * g4.y + b4.y;
      float o2 = d[2] * rstd * g4.z + b4.z;
      float o3 = d[3] * rstd * g4.w + b4.w;
      uint2 pack;
      pack.x = (unsigned int)f2bf(o0) | ((unsigned int)f2bf(o1) << 16);
      pack.y = (unsigned int)f2bf(o2) | ((unsigned int)f2bf(o3) << 16);
      // fragment-packed write: node w -> block B=w>>4, m=w&15;
      // channels c..c+3: kt=sl>>3, q=(sl>>1)&3, half8=(sl&1)*4
      int kt = sl >> 3;
      int qq = (sl >> 1) & 3;
      size_t elem = (size_t)(w >> 4) * 2048 + kt * 512 + (qq * 16 + (w & 15)) * 8 + (sl & 1) * 4;
      *(uint2*)&xnext_pack[elem] = pack;
    }
  }
}

// ---------------- graph max-pool (relu implicit: atomicMax vs 0-init) ----------------
__global__ void k_pool(const float* __restrict__ emb, const int* __restrict__ batch,
                       float* __restrict__ pooled, int N) {
  int c = threadIdx.x & 127;
  int half = threadIdx.x >> 7;
  int base = blockIdx.x * 64 + half;
  int limit = min(blockIdx.x * 64 + 64, N);
  float cur = 0.f;
  int curg = -1;
  for (int n = base; n < limit; n += 2) {
    int g = batch[n];
    if (g != curg) {
      if (curg >= 0) atomicMax((unsigned int*)&pooled[curg * 128 + c], __float_as_uint(cur));
      curg = g;
      cur = 0.f;
    }
    cur = fmaxf(cur, emb[(size_t)n * 128 + c]);
  }
  if (curg >= 0) atomicMax((unsigned int*)&pooled[curg * 128 + c], __float_as_uint(cur));
}

// ---------------- MLP: 128 -> 32 -> 32 -> 32 -> 1 ----------------
__global__ void k_mlp(const float* __restrict__ pooled,
                      const float* __restrict__ pw1, const float* __restrict__ pb1,
                      const float* __restrict__ pw2, const float* __restrict__ pb2,
                      const float* __restrict__ pw3, const float* __restrict__ pb3,
                      const float* __restrict__ pw4, const float* __restrict__ pb4,
                      float* __restrict__ out) {
  int g = blockIdx.x;
  int t = threadIdx.x;  // 64 threads
  __shared__ float buf1[32], buf2[32];
  if (t < 32) {
    float acc = pb1[t];
    for (int k = 0; k < 128; ++k) acc += pw1[t * 128 + k] * pooled[g * 128 + k];
    buf1[t] = fmaxf(acc, 0.f);
  }
  __syncthreads();
  if (t < 32) {
    float acc = pb2[t];
    for (int k = 0; k < 32; ++k) acc += pw2[t * 32 + k] * buf1[k];
    buf2[t] = fmaxf(acc, 0.f);
  }
  __syncthreads();
  if (t < 32) {
    float acc = pb3[t];
    for (int k = 0; k < 32; ++k) acc += pw3[t * 32 + k] * buf2[k];
    buf1[t] = fmaxf(acc, 0.f);
  }
  __syncthreads();
  if (t == 0) {
    float acc = pb4[0];
    for (int k = 0; k < 32; ++k) acc += pw4[k] * buf1[k];
    out[g] = acc;
  }
}

// ---------------------------------------------------------------------------

extern "C" void kernel_launch(void* const* d_in, const int* in_sizes, int n_in,
                              void* d_out, int out_size, void* d_ws, size_t ws_size,
                              hipStream_t stream) {
  const float* x_in = (const float*)d_in[0];
  const int* ei = (const int*)d_in[1];
  const int* batch = (const int*)d_in[2];
  const float* ea = (const float*)d_in[3];

  const int N = in_sizes[0] / 128;
  const int E = in_sizes[1] / 2;
  const int EP = E + N;
  const int G = out_size - N * 128;
  const int NBUK = (N + 255) / 256;
  const int NBINA = (E + CHUNK - 1) / CHUNK;

  const float *Wl[3], *bl[3], *Wr[3], *br[3], *We[3], *att[3], *bo[3];
  for (int l = 0; l < 3; ++l) {
    Wl[l] = (const float*)d_in[4 + 7 * l];
    bl[l] = (const float*)d_in[5 + 7 * l];
    Wr[l] = (const float*)d_in[6 + 7 * l];
    br[l] = (const float*)d_in[7 + 7 * l];
    We[l] = (const float*)d_in[8 + 7 * l];
    att[l] = (const float*)d_in[9 + 7 * l];
    bo[l] = (const float*)d_in[10 + 7 * l];
  }
  const float* lng[2] = {(const float*)d_in[25], (const float*)d_in[27]};
  const float* lnb[2] = {(const float*)d_in[26], (const float*)d_in[28]};
  const float* pw1 = (const float*)d_in[29];
  const float* pb1 = (const float*)d_in[30];
  const float* pw2 = (const float*)d_in[31];
  const float* pb2 = (const float*)d_in[32];
  const float* pw3 = (const float*)d_in[33];
  const float* pb3 = (const float*)d_in[34];
  const float* pw4 = (const float*)d_in[35];
  const float* pb4 = (const float*)d_in[36];

  char* base = (char*)d_ws;
  size_t cur = 0;
  auto carve = [&](size_t bytes) -> char* {
    char* p = base + cur;
    cur += (bytes + 255) & ~(size_t)255;
    return p;
  };
  unsigned short* xlb = (unsigned short*)carve((size_t)N * 128 * 2);
  unsigned short* xrb = (unsigned short*)carve((size_t)N * 128 * 2);
  // xpack: fragment-packed inter-layer activations; +1 block slack for tail
  unsigned short* xpack = (unsigned short*)carve(((size_t)((N + 15) / 16) + 1) * 2048 * 2);
  unsigned short* Wb = (unsigned short*)carve((size_t)6 * 16384 * 2);
  float4* e4 = (float4*)carve((size_t)(EP + 8) * 16);  // +8 pad records
  float4* staged = (float4*)carve((size_t)NBUK * BCAP * 16);
  int* offs = (int*)carve((size_t)(N + 1) * 4);
  int* gcnt = (int*)carve((size_t)NBUK * 4);
  float* scoreTab = (float*)carve((size_t)3 * 512 * 4);
  float* pooled = (float*)carve((size_t)G * 128 * 4);

  float* emb_out = (float*)d_out;
  float* mlp_out = (float*)d_out + (size_t)N * 128;

  hipMemsetAsync(gcnt, 0, (size_t)NBUK * 4, stream);
  hipMemsetAsync(pooled, 0, (size_t)G * 128 * 4, stream);

  // packed prologue: binA blocks + packed-convW blocks + 1 pack block
  k_pre<<<NBINA + 48 + 1, 256, 0, stream>>>(ei, ea, gcnt, staged, E, NBUK, NBINA,
                                            Wl[0], Wr[0], Wl[1], Wr[1], Wl[2], Wr[2], Wb,
                                            We[0], att[0], We[1], att[1], We[2], att[2],
                                            scoreTab);
  k_binB<<<NBUK, 512, 0, stream>>>(staged, gcnt, e4, offs, N, NBUK, EP);

  for (int l = 0; l < 3; ++l) {
    dim3 ggrid((N + 63) / 64);
    if (l == 0) {
      k_gemm_fused<true><<<ggrid, 256, 0, stream>>>(x_in, xpack, Wb, bl[0], br[0], xlb, xrb, N);
    } else {
      k_gemm_fused<false><<<ggrid, 256, 0, stream>>>(nullptr, xpack, Wb + (size_t)l * 32768,
                                                     bl[l], br[l], xlb, xrb, N);
    }
    int last = (l == 2) ? 1 : 0;
    const float* g = last ? bo[l] : lng[l];
    const float* b = last ? bo[l] : lnb[l];
    k_agg<<<(N * 64 + 255) / 256, 256, 0, stream>>>(xlb, xrb, e4, offs,
                                                    scoreTab + (size_t)l * 512,
                                                    bo[l], g, b,
                                                    xpack, emb_out, last, N);
  }

  k_pool<<<(N + 63) / 64, 256, 0, stream>>>(emb_out, batch, pooled, N);
  k_mlp<<<G, 64, 0, stream>>>(pooled, pw1, pb1, pw2, pb2, pw3, pb3, pw4, pb4, mlp_out);
}